// Round 1
// baseline (117.786 us; speedup 1.0000x reference)
//
#include <hip/hip_runtime.h>
#include <cstdint>

// y[m][n] = sum_k x[m][k] * (q[n][k] * scale[n]) + bias[n]
// M=32, K=8192, N=8192; q = signed int4 nibbles packed 8 per int32.
// Harness dtype reality (verified round 4): fp16 tensors are FLOAT32 on
// device (inputs and output); b_packed is int32.
//
// Round 5: FUSED single-dispatch kernel. The 268 MB workspace re-poison
// (~45 us fillBuffer, in the timed graph) is harness-fixed; our controllable
// span was xprep + qgemm_xp. This version removes the xprep dispatch + its
// workspace round-trip: A is read directly from x (f32, 1 MB, L2-resident)
// and converted to the nibble-permuted f16 fragment in-register (the proven
// qgemm_direct math) inside the proven qgemm_xp structure (16-wave k-split,
// all-B prefetch at t=0). Workspace is untouched.
#define M_DIM 32
#define K_DIM 8192
#define N_DIM 8192

typedef _Float16 f16x8 __attribute__((ext_vector_type(8)));
typedef _Float16 f16x2 __attribute__((ext_vector_type(2)));
typedef float    f32x4 __attribute__((ext_vector_type(4)));

__device__ __forceinline__ uint32_t u4e(uint4 v, int t) {
  return (t == 0) ? v.x : (t == 1) ? v.y : (t == 2) ? v.z : v.w;
}

// Magic-bias dequant: dword (8 nibbles) -> 8 exact f16 in [-8,7].
// t_s = ((w>>4s) & 0x000F000F) ^ 0x64086408 = f16x2 {1024+(n_s^8), 1024+(n_{s+4}^8)}
// minus 1032.0 -> {val(n_s), val(n_{s+4})} exactly (integers < 2048, exact f16).
// Fragment element j therefore holds nibble kp[j] = (j>>1) + (j&1)*4; the A
// fragment build below bakes the SAME permutation, so the MFMA dot is exact.
__device__ __forceinline__ f16x8 dq8(uint32_t w) {
  union { uint32_t u[4]; f16x8 v; } r;
  const uint32_t MASK  = 0x000F000Fu;
  const uint32_t MAGIC = 0x64086408u;                 // f16x2 {1032, 1032}
  const f16x2 magic = __builtin_bit_cast(f16x2, MAGIC);
#pragma unroll
  for (int s = 0; s < 4; ++s) {
    uint32_t t = ((w >> (4 * s)) & MASK) ^ MAGIC;
    f16x2 h = __builtin_bit_cast(f16x2, t) - magic;   // v_pk_add_f16 (neg)
    r.u[s] = __builtin_bit_cast(uint32_t, h);
  }
  return r.v;
}

// -------- fused GEMM: 256 WGs x 1024 thr (16 waves) ------------------------
// WG = 32 cols (n) x 32 rows (m); 16 waves k-split (512 k each).
// All 8 B uint4 prefetched up front (whole WG HBM demand in flight at t=0).
// A: direct f32 loads from x, depth-1 pipeline; carried state is the
// CONVERTED f16x8 pair (8 VGPRs) so only the 8 in-flight f32x4 (32 VGPRs)
// add pressure -> est ~112 VGPRs, under the 128 cap (1024 thr, 4 waves/EU).
// k mapping, identical on both operands (exact dot):
//   k = w*512 + c*128 + quad*32 + t*8 + kp[j],  kp[j] = (j>>1) + (j&1)*4
__global__ __launch_bounds__(1024, 4) void qgemm_fused(
    const uint32_t* __restrict__ bq,     // packed int4 [N, K/8]
    const float*    __restrict__ x,      // f32 [32, 8192]
    const float*    __restrict__ sc,     // f32 [8192]
    const float*    __restrict__ bi,     // f32 [8192]
    float*          __restrict__ out) {  // f32 [32, 8192]
  __shared__ float red[16][32][33];      // [wave][n][m], stride 33 (66 KB)

  const int tid  = threadIdx.x;
  const int w    = tid >> 6;             // wave 0..15 -> k0 = w*512
  const int lane = tid & 63;
  const int l16  = lane & 15;
  const int quad = lane >> 4;
  const int n0   = blockIdx.x << 5;      // 32 n per WG

  // A f32 base: rows l16 / l16+16, k base = w*512 + quad*32 (+ c*128 + t*8).
  const float* ap0 = x + (size_t)l16 * K_DIM + (w << 9) + (quad << 5);
  const float* ap1 = ap0 + (size_t)16 * K_DIM;

  // Issue A(g=0) first (L2-latency class), then the 8 HBM B loads.
  f32x4 l0 = *(const f32x4*)(ap0);
  f32x4 h0 = *(const f32x4*)(ap0 + 4);
  f32x4 l1 = *(const f32x4*)(ap1);
  f32x4 h1 = *(const f32x4*)(ap1 + 4);

  // B uint4 index: row*256 + w*16 + c*4 + quad; rows n0+l16, n0+l16+16.
  const uint4* bq4 = (const uint4*)bq;
  const uint4* bp0 = bq4 + (size_t)(n0 + l16) * 256 + (w << 4) + quad;
  const uint4* bp1 = bp0 + (size_t)16 * 256;
  uint4 b0[4], b1[4];
#pragma unroll
  for (int c = 0; c < 4; ++c) { b0[c] = bp0[c * 4]; b1[c] = bp1[c * 4]; }

  // Convert A(g=0) to the nibble-pair-permuted f16 fragments.
  f16x8 fa0c, fa1c;
#pragma unroll
  for (int s = 0; s < 4; ++s) {
    fa0c[2 * s] = (_Float16)l0[s]; fa0c[2 * s + 1] = (_Float16)h0[s];
    fa1c[2 * s] = (_Float16)l1[s]; fa1c[2 * s + 1] = (_Float16)h1[s];
  }

  f32x4 acc00 = {0.f, 0.f, 0.f, 0.f};
  f32x4 acc01 = {0.f, 0.f, 0.f, 0.f};
  f32x4 acc10 = {0.f, 0.f, 0.f, 0.f};
  f32x4 acc11 = {0.f, 0.f, 0.f, 0.f};

#pragma unroll
  for (int g = 0; g < 16; ++g) {
    const int gn  = (g + 1) & 15;        // last iter refetches g0 (harmless L2 hit)
    const int off = (gn >> 2) * 128 + (gn & 3) * 8;
    f32x4 nl0 = *(const f32x4*)(ap0 + off);
    f32x4 nh0 = *(const f32x4*)(ap0 + off + 4);
    f32x4 nl1 = *(const f32x4*)(ap1 + off);
    f32x4 nh1 = *(const f32x4*)(ap1 + off + 4);

    const int c = g >> 2, t = g & 3;
    f16x8 fb0 = dq8(u4e(b0[c], t));
    f16x8 fb1 = dq8(u4e(b1[c], t));
    acc00 = __builtin_amdgcn_mfma_f32_16x16x32_f16(fa0c, fb0, acc00, 0, 0, 0);
    acc01 = __builtin_amdgcn_mfma_f32_16x16x32_f16(fa1c, fb0, acc01, 0, 0, 0);
    acc10 = __builtin_amdgcn_mfma_f32_16x16x32_f16(fa0c, fb1, acc10, 0, 0, 0);
    acc11 = __builtin_amdgcn_mfma_f32_16x16x32_f16(fa1c, fb1, acc11, 0, 0, 0);

    // Convert next A (compiler places the vmcnt wait here, after MFMA issue;
    // in-wave program order means the MFMAs above read the OLD fa values).
#pragma unroll
    for (int s = 0; s < 4; ++s) {
      fa0c[2 * s] = (_Float16)nl0[s]; fa0c[2 * s + 1] = (_Float16)nh0[s];
      fa1c[2 * s] = (_Float16)nl1[s]; fa1c[2 * s + 1] = (_Float16)nh1[s];
    }
  }

  // C/D layout (verified round 4): n = lane&15, m = quad*4 + r.
#pragma unroll
  for (int r = 0; r < 4; ++r) {
    const int mr = (quad << 2) + r;
    red[w][l16][mr]           = acc00[r];
    red[w][l16][mr + 16]      = acc01[r];
    red[w][l16 + 16][mr]      = acc10[r];
    red[w][l16 + 16][mr + 16] = acc11[r];
  }

  __syncthreads();

  // 1024 threads = one output each: n = tid&31, m = tid>>5; stride-33 rows
  // make the 16-way read conflict-free across lanes.
  const int n = tid & 31;
  const int m = tid >> 5;
  float s = 0.f;
#pragma unroll
  for (int ww = 0; ww < 16; ++ww) s += red[ww][n][m];
  const int gn = n0 + n;
  out[(size_t)m * N_DIM + gn] = fmaf(s, sc[gn], bi[gn]);
}

extern "C" void kernel_launch(void* const* d_in, const int* in_sizes, int n_in,
                              void* d_out, int out_size, void* d_ws, size_t ws_size,
                              hipStream_t stream) {
  const float*    x  = (const float*)d_in[0];     // f32 [32,8192]
  const uint32_t* bq = (const uint32_t*)d_in[1];  // int32 [8192,1024]
  const float*    sc = (const float*)d_in[2];     // f32 [8192]
  const float*    bi = (const float*)d_in[3];     // f32 [8192]
  float*          y  = (float*)d_out;             // f32 [32,8192]
  (void)d_ws; (void)ws_size;                      // workspace deliberately unused

  qgemm_fused<<<N_DIM / 32, 1024, 0, stream>>>(bq, x, sc, bi, y);
}

// Round 2
// 93.175 us; speedup vs baseline: 1.2641x; 1.2641x over previous
//
#include <hip/hip_runtime.h>
#include <cstdint>

// y[m][n] = sum_k x[m][k] * (q[n][k] * scale[n]) + bias[n]
// M=32, K=8192, N=8192; q = signed int4 nibbles packed 8 per int32.
// Harness dtype reality (verified round 4): fp16 tensors are FLOAT32 on
// device (inputs and output); b_packed is int32. ws_size ~268 MB.
//
// Round 6: revert to the verified xprep+xp-GEMM structure (round-1 proved the
// fused A-direct path is a 64-line gather: 54 us, all pipes <7%). Structural
// change vs round 0: WG = 16n (grid 512) instead of 32n (grid 256), with
// __launch_bounds__(1024, 8) capping VGPRs at 64. This gives 2 WGs/CU
// (2048 thr, ~70 KB LDS) = 100% occupancy target instead of the round-0
// 128-VGPR / 1-WG/CU / 50% ceiling. Per-wave work halves (4 B-uint4 prefetch,
// 1 dq8 + 2 MFMA per iter) -> ~55 VGPR demand, under the 64 cap.
#define M_DIM 32
#define K_DIM 8192
#define N_DIM 8192

typedef _Float16 f16x8 __attribute__((ext_vector_type(8)));
typedef _Float16 f16x2 __attribute__((ext_vector_type(2)));
typedef float    f32x4 __attribute__((ext_vector_type(4)));

__device__ __forceinline__ uint32_t u4e(uint4 v, int t) {
  return (t == 0) ? v.x : (t == 1) ? v.y : (t == 2) ? v.z : v.w;
}

// Magic-bias dequant: dword (8 nibbles) -> 8 exact f16 in [-8,7].
// t_s = ((w>>4s) & 0x000F000F) ^ 0x64086408 = f16x2 {1024+(n_s^8), 1024+(n_{s+4}^8)}
// minus 1032.0 -> {val(n_s), val(n_{s+4})} exactly (integers < 2048, exact f16).
// Fragment element j therefore holds nibble kp[j] = (j>>1) + (j&1)*4; xprep
// bakes the SAME permutation into the A layout, so the MFMA dot is exact.
__device__ __forceinline__ f16x8 dq8(uint32_t w) {
  union { uint32_t u[4]; f16x8 v; } r;
  const uint32_t MASK  = 0x000F000Fu;
  const uint32_t MAGIC = 0x64086408u;                 // f16x2 {1032, 1032}
  const f16x2 magic = __builtin_bit_cast(f16x2, MAGIC);
#pragma unroll
  for (int s = 0; s < 4; ++s) {
    uint32_t t = ((w >> (4 * s)) & MASK) ^ MAGIC;
    f16x2 h = __builtin_bit_cast(f16x2, t) - magic;   // v_pk_add_f16 (neg)
    r.u[s] = __builtin_bit_cast(uint32_t, h);
  }
  return r.v;
}

// -------- x prep: f32 x[32][8192] -> f16 xp[g=k/8][m][8], nibble-pair perm --
// Element j of each 8-group = x[k = g*8 + (j>>1) + (j&1)*4]  (interleave lo/hi).
__global__ __launch_bounds__(256) void xprep_kernel(
    const float* __restrict__ x, uint4* __restrict__ xp) {
  const int T = blockIdx.x * 256 + threadIdx.x;  // 0..32767
  const int m = T >> 10;                         // 0..31
  const int g = T & 1023;                        // 0..1023
  const f32x4* p = (const f32x4*)(x + (size_t)m * K_DIM + (size_t)g * 8);
  f32x4 lo = p[0], hi = p[1];
  union { uint4 q; f16x8 v; } o;
#pragma unroll
  for (int s = 0; s < 4; ++s) {
    o.v[2 * s]     = (_Float16)lo[s];            // nibble-pair perm: {lo_s, hi_s}
    o.v[2 * s + 1] = (_Float16)hi[s];
  }
  xp[(size_t)g * 32 + m] = o.q;
}

// -------- main GEMM: 512 WGs x 1024 thr (16 waves), 16 n per WG ------------
// Wave w handles k in [w*512, w*512+512): 16 g-iterations of k=32.
// All 4 B uint4 prefetched up front (wave's whole HBM demand in flight at t=0).
// k-scramble: slot (c,t,quad,j) takes k = (w*64+c*16+quad*4+t)*8 + kp[j]
// from BOTH operands — same bijection, exact dot product.
__global__ __launch_bounds__(1024, 8) void qgemm_xp16(
    const uint32_t* __restrict__ bq,     // packed int4 [N, K/8]
    const uint4*    __restrict__ xp,     // f16 [1024][32][8] (perm'd)
    const float*    __restrict__ sc,     // f32 [8192]
    const float*    __restrict__ bi,     // f32 [8192]
    float*          __restrict__ out) {  // f32 [32, 8192]
  __shared__ float red[16][16][34];      // [wave][n][m], stride 34 (~35 KB)

  const int tid  = threadIdx.x;
  const int w    = tid >> 6;             // wave 0..15 -> k0 = w*512
  const int lane = tid & 63;
  const int l16  = lane & 15;
  const int quad = lane >> 4;
  const int n0   = blockIdx.x << 4;      // 16 n per WG

  // B uint4 index: row*256 + w*16 + c*4 + quad; rows n0+l16 (one n-tile).
  const uint4* bq4 = (const uint4*)bq;
  const uint4* bp0 = bq4 + (size_t)(n0 + l16) * 256 + (w << 4) + quad;
  // A uint4 index: g*32 + m; g = w*64 + quad*4 + c*16 + t; m = l16 (+16).
  const uint4* ap  = xp + (size_t)(((w << 6) + (quad << 2)) * 32 + l16);

  // Prefetch ALL B for this wave: 4 outstanding HBM loads (perfectly
  // coalesced: 64 lanes -> 16 x 64B lines).
  uint4 b0[4];
#pragma unroll
  for (int c = 0; c < 4; ++c) b0[c] = bp0[c * 4];

  f32x4 acc0 = {0.f, 0.f, 0.f, 0.f};    // m 0..15
  f32x4 acc1 = {0.f, 0.f, 0.f, 0.f};    // m 16..31

  // A loads are L2 hits (xp = 512 KB, just written). Full unroll lets the
  // compiler pipeline them as deep as the 64-reg budget allows.
#pragma unroll
  for (int g = 0; g < 16; ++g) {
    const int c   = g >> 2, t = g & 3;
    const int off = (c * 16 + t) * 32;
    uint4 a0 = ap[off];
    uint4 a1 = ap[off + 16];
    f16x8 fb  = dq8(u4e(b0[c], t));
    f16x8 fa0 = __builtin_bit_cast(f16x8, a0);
    f16x8 fa1 = __builtin_bit_cast(f16x8, a1);
    acc0 = __builtin_amdgcn_mfma_f32_16x16x32_f16(fa0, fb, acc0, 0, 0, 0);
    acc1 = __builtin_amdgcn_mfma_f32_16x16x32_f16(fa1, fb, acc1, 0, 0, 0);
  }

  // C/D layout (verified round 4): n = lane&15, m = quad*4 + r.
#pragma unroll
  for (int r = 0; r < 4; ++r) {
    const int mr = (quad << 2) + r;
    red[w][l16][mr]      = acc0[r];
    red[w][l16][mr + 16] = acc1[r];
  }

  __syncthreads();

  // 512 outputs (16 n x 32 m): threads 0..511 take one each; stride-34 rows
  // keep the 16-way read <=2-way bank-conflicted.
  if (tid < 512) {
    const int n = tid & 15;
    const int m = tid >> 4;
    float s = 0.f;
#pragma unroll
    for (int ww = 0; ww < 16; ++ww) s += red[ww][n][m];
    const int gn = n0 + n;
    out[(size_t)m * N_DIM + gn] = fmaf(s, sc[gn], bi[gn]);
  }
}

// -------- fallback (tiny ws): round-4 known-good direct kernel -------------
__global__ __launch_bounds__(512) void qgemm_direct(
    const uint32_t* __restrict__ bq, const float* __restrict__ x,
    const float* __restrict__ sc, const float* __restrict__ bi,
    float* __restrict__ out) {
  __shared__ float red[8][32][40];
  const int tid  = threadIdx.x;
  const int w    = tid >> 6;
  const int lane = tid & 63;
  const int l16  = lane & 15;
  const int quad = lane >> 4;
  const int n0   = blockIdx.x << 5;

  const uint4* bq4 = (const uint4*)bq;
  const uint4* bp0 = bq4 + (size_t)(n0 + l16) * 256 + (w << 5) + quad;
  const uint4* bp1 = bp0 + (size_t)16 * 256;
  const float* ap0 = x + (size_t)l16 * K_DIM + (w << 10) + (quad << 5);
  const float* ap1 = ap0 + (size_t)16 * K_DIM;

  f32x4 acc00 = {0.f,0.f,0.f,0.f}, acc01 = {0.f,0.f,0.f,0.f};
  f32x4 acc10 = {0.f,0.f,0.f,0.f}, acc11 = {0.f,0.f,0.f,0.f};
#pragma unroll
  for (int c = 0; c < 8; ++c) {
    const uint4 wb0 = bp0[c * 4];
    const uint4 wb1 = bp1[c * 4];
#pragma unroll
    for (int t = 0; t < 4; ++t) {
      const float* a0 = ap0 + c * 128 + t * 8;
      const float* a1 = ap1 + c * 128 + t * 8;
      f32x4 l0 = *(const f32x4*)a0, h0 = *(const f32x4*)(a0 + 4);
      f32x4 l1 = *(const f32x4*)a1, h1 = *(const f32x4*)(a1 + 4);
      f16x8 fa0, fa1;
#pragma unroll
      for (int s = 0; s < 4; ++s) {
        fa0[2*s] = (_Float16)l0[s]; fa0[2*s+1] = (_Float16)h0[s];
        fa1[2*s] = (_Float16)l1[s]; fa1[2*s+1] = (_Float16)h1[s];
      }
      f16x8 fb0 = dq8(u4e(wb0, t));
      f16x8 fb1 = dq8(u4e(wb1, t));
      acc00 = __builtin_amdgcn_mfma_f32_16x16x32_f16(fa0, fb0, acc00, 0, 0, 0);
      acc01 = __builtin_amdgcn_mfma_f32_16x16x32_f16(fa1, fb0, acc01, 0, 0, 0);
      acc10 = __builtin_amdgcn_mfma_f32_16x16x32_f16(fa0, fb1, acc10, 0, 0, 0);
      acc11 = __builtin_amdgcn_mfma_f32_16x16x32_f16(fa1, fb1, acc11, 0, 0, 0);
    }
  }
#pragma unroll
  for (int r = 0; r < 4; ++r) {
    const int mr = (quad << 2) + r;
    red[w][l16][mr]           = acc00[r];
    red[w][l16][mr + 16]      = acc01[r];
    red[w][l16 + 16][mr]      = acc10[r];
    red[w][l16 + 16][mr + 16] = acc11[r];
  }
  __syncthreads();
  const int n  = tid & 31;
  const int mh = tid >> 5;
  float s0 = 0.f, s1 = 0.f;
#pragma unroll
  for (int ww = 0; ww < 8; ++ww) { s0 += red[ww][n][mh]; s1 += red[ww][n][mh+16]; }
  const int gn = n0 + n;
  out[(size_t)mh * N_DIM + gn]        = fmaf(s0, sc[gn], bi[gn]);
  out[(size_t)(mh + 16) * N_DIM + gn] = fmaf(s1, sc[gn], bi[gn]);
}

extern "C" void kernel_launch(void* const* d_in, const int* in_sizes, int n_in,
                              void* d_out, int out_size, void* d_ws, size_t ws_size,
                              hipStream_t stream) {
  const float*    x  = (const float*)d_in[0];     // f32 [32,8192]
  const uint32_t* bq = (const uint32_t*)d_in[1];  // int32 [8192,1024]
  const float*    sc = (const float*)d_in[2];     // f32 [8192]
  const float*    bi = (const float*)d_in[3];     // f32 [8192]
  float*          y  = (float*)d_out;             // f32 [32,8192]

  const size_t XP_BYTES = (size_t)M_DIM * K_DIM * 2;  // 512 KB f16
  if (ws_size >= XP_BYTES) {                          // constant -> graph-safe
    uint4* xp = (uint4*)d_ws;
    xprep_kernel<<<128, 256, 0, stream>>>(x, xp);
    qgemm_xp16<<<N_DIM / 16, 1024, 0, stream>>>(bq, xp, sc, bi, y);
  } else {
    qgemm_direct<<<N_DIM / 32, 512, 0, stream>>>(bq, x, sc, bi, y);
  }
}